// Round 8
// baseline (42.803 us; speedup 1.0000x reference)
//
#include <hip/hip_runtime.h>

typedef unsigned short u16;
typedef unsigned int   u32;
typedef __fp16 h2t __attribute__((ext_vector_type(2)));

#define D      300
#define L      256
#define LT     8
#define B      256
#define NHOPS  6
#define NCLS   3
#define NT     1024

// LDS layout (bytes)
#define OFF_E    0          // u32 [128 lp][300 col] f16x2 pairs  153600
#define OFF_VEC  153600     // f32 [312] (300 + zero pad)          1248
#define OFF_VPK  154848     // u32 [12 chunks][20] vec f16 pairs    960
#define OFF_APK  155808     // u32 [12 chunks][12] alpha f16 pairs  576
#define OFF_S0   156384     // f32 [256]                           1024
#define OFF_CTX  157408     // i32 [256]                           1024
#define SMEM_BYTES 158432

#define DPP_ADD(x, ctrl) \
    x += __int_as_float(__builtin_amdgcn_update_dpp(0, __float_as_int(x), ctrl, 0xf, 0xf, true))

__device__ __forceinline__ float dpp_wave_sum(float x) {
    DPP_ADD(x, 0x111);   // row_shr:1
    DPP_ADD(x, 0x112);   // row_shr:2
    DPP_ADD(x, 0x114);   // row_shr:4
    DPP_ADD(x, 0x118);   // row_shr:8
    DPP_ADD(x, 0x142);   // row_bcast:15
    DPP_ADD(x, 0x143);   // row_bcast:31
    return x;            // lane 63 holds the full 64-lane sum
}
__device__ __forceinline__ float lane63(float x) {
    return __int_as_float(__builtin_amdgcn_readlane(__float_as_int(x), 63));
}
__device__ __forceinline__ u32 pk16(float a, float b) {
    h2t r = __builtin_amdgcn_cvt_pkrtz(a, b);
    return __builtin_bit_cast(u32, r);
}
__device__ __forceinline__ float fdot2(u32 a, u32 b, float c) {
    return __builtin_amdgcn_fdot2(__builtin_bit_cast(h2t, a),
                                  __builtin_bit_cast(h2t, b), c, false);
}

__launch_bounds__(NT, 1)
__global__ void memnet_main(
    const float* __restrict__ emb,
    const float* __restrict__ w_lin,
    const float* __restrict__ b_lin,
    const float* __restrict__ w_att,
    const float* __restrict__ b_att,
    const float* __restrict__ w_out,
    const float* __restrict__ b_out,
    const int* __restrict__ ctx_ids,
    const int* __restrict__ ctx_len,
    const int* __restrict__ tgt_ids,
    const int* __restrict__ tgt_len,
    const int* __restrict__ tgt_loc,
    float* __restrict__ out)
{
    extern __shared__ char sm[];
    float* vec_ = (float*)(sm + OFF_VEC);
    u32*   vpk_ = (u32*)(sm + OFF_VPK);
    u32*   apk_ = (u32*)(sm + OFF_APK);
    float* s0_  = (float*)(sm + OFF_S0);
    int*   ctx_ = (int*)(sm + OFF_CTX);

    const int b = blockIdx.x, t = threadIdx.x;
    const int lane = t & 63, wv = t >> 6;
    const int c  = lane / 5;            // chunk 0..11 (lane<60)
    const int qi = lane - 5 * c;
    const int q  = 5 * wv + qi;         // column quad (heavy)
    const bool heavy = (wv < 15) && (lane < 60);

    const int clen = ctx_len[b], tlen = tgt_len[b], loc = tgt_loc[b];
    const int lps  = (clen + 1) >> 1;   // staged l-pairs

    const float4 z4 = make_float4(0.f, 0.f, 0.f, 0.f);

    // ---------------- init ----------------
    if (t < L) { ctx_[t] = ctx_ids[b * L + t]; s0_[t] = 0.f; }
    if (t >= 300 && t < 312) vec_[t] = 0.f;
    if (t >= 768 && t < 1008) vpk_[t - 768] = 0;   // zero all 240 slots
    __syncthreads();

    // ---------------- staging: E pairs (f16x2, vloc-premult) + s0 ----------------
    {
        float4 wa1 = ((const float4*)w_att)[lane];
        float4 wa2 = z4;
        if (lane < 11) wa2 = ((const float4*)w_att)[64 + lane];
        const float rclen = 1.f / (float)clen;
        for (int lp = wv; lp < lps; lp += 16) {
            const int l0 = 2 * lp, l1 = l0 + 1;
            const float4* e0 = (const float4*)(emb + (long)ctx_[l0] * D);
            const float4* e1 = (const float4*)(emb + (long)ctx_[l1] * D);
            const float4 a0 = e0[lane];
            const float4 a1 = e1[lane];
            float4 b0 = z4, b1 = z4;
            if (lane < 11) { b0 = e0[64 + lane]; b1 = e1[64 + lane]; }
            float d0 = a0.x*wa1.x + a0.y*wa1.y + a0.z*wa1.z + a0.w*wa1.w
                     + b0.x*wa2.x + b0.y*wa2.y + b0.z*wa2.z + b0.w*wa2.w;
            float d1 = a1.x*wa1.x + a1.y*wa1.y + a1.z*wa1.z + a1.w*wa1.w
                     + b1.x*wa2.x + b1.y*wa2.y + b1.z*wa2.z + b1.w*wa2.w;
            d0 = dpp_wave_sum(d0);
            d1 = dpp_wave_sum(d1);
            const float vl0 = 1.f - fabsf((float)(l0 - loc)) * rclen; // l0 < clen
            const float vl1 = (l1 < clen) ? 1.f - fabsf((float)(l1 - loc)) * rclen : 0.f;
            if (lane == 63) { s0_[l0] = vl0 * d0; s0_[l1] = vl1 * d1; }
            uint4 P;
            P.x = pk16(a0.x * vl0, a1.x * vl1);
            P.y = pk16(a0.y * vl0, a1.y * vl1);
            P.z = pk16(a0.z * vl0, a1.z * vl1);
            P.w = pk16(a0.w * vl0, a1.w * vl1);
            *(uint4*)(sm + OFF_E + (lp * 300 + 4 * lane) * 4) = P;
            if (lane < 11) {
                uint4 Q;
                Q.x = pk16(b0.x * vl0, b1.x * vl1);
                Q.y = pk16(b0.y * vl0, b1.y * vl1);
                Q.z = pk16(b0.z * vl0, b1.z * vl1);
                Q.w = pk16(b0.w * vl0, b1.w * vl1);
                *(uint4*)(sm + OFF_E + (lp * 300 + 256 + 4 * lane) * 4) = Q;
            }
        }
    }

    // ---------------- v_aspect -> vec (f32 + padded f16 pairs) ----------------
    if (t < D) {
        int ids[LT];
        #pragma unroll
        for (int j = 0; j < LT; ++j) ids[j] = tgt_ids[b * LT + j];  // uniform -> s_load
        float s = 0.f;
        #pragma unroll
        for (int j = 0; j < LT; ++j) {
            const int  safe = (j < tlen) ? ids[j] : ids[0];
            const float msk = (j < tlen) ? 1.f : 0.f;
            s += msk * emb[(long)safe * D + t];
        }
        const float v = s / (float)tlen;
        vec_[t] = v;
        const float v2 = __shfl_xor(v, 1);
        if ((t & 1) == 0) {
            const int kp = t >> 1;
            const int cp = kp / 13, sl = kp - 13 * cp;
            vpk_[20 * cp + sl] = pk16(v, v2);
        }
    }

    // ---------------- W pack into registers (f16 pairs, reused 6 hops) ----
    uint4 wreg[13];
    if (heavy) {
        #pragma unroll
        for (int i = 0; i < 13; ++i) {
            const int k0 = 26 * c + 2 * i;
            float4 w0 = z4, w1 = z4;
            if (k0 < D)     w0 = *(const float4*)(w_lin + (long)k0 * D + 4 * q);
            if (k0 + 1 < D) w1 = *(const float4*)(w_lin + (long)(k0 + 1) * D + 4 * q);
            wreg[i].x = pk16(w0.x, w1.x);
            wreg[i].y = pk16(w0.y, w1.y);
            wreg[i].z = pk16(w0.z, w1.z);
            wreg[i].w = pk16(w0.w, w1.w);
        }
    }

    float4 blin4 = z4;
    if (heavy) blin4 = *(const float4*)(b_lin + 4 * q);
    __syncthreads();   // E, s0, vec, vpk ready

    // ---------------- E slice -> registers (read LDS E once, reuse 6 hops) ----
    const int lp0 = 11 * c;
    uint4 ereg[11];
    if (heavy) {
        const char* ep = sm + OFF_E + (lp0 * 300 + 4 * q) * 4;
        #pragma unroll
        for (int r = 0; r < 11; ++r) {
            ereg[r] = make_uint4(0u, 0u, 0u, 0u);
            if (lp0 + r < lps) ereg[r] = *(const uint4*)(ep + r * 1200);
        }
    }

    float4 s0r = z4, wb1 = z4, wb2 = z4;
    float batt = 0.f;
    if (wv == 15) {
        s0r = *(const float4*)(s0_ + 4 * lane);
        wb1 = *(const float4*)(w_att + D + 4 * lane);
        if (lane < 11) wb2 = *(const float4*)(w_att + D + 256 + 4 * lane);
        batt = b_att[0];
    }

    // ---------------- hops ----------------
    for (int hop = 0; hop < NHOPS; ++hop) {
        float4 acc = z4;
        if (heavy) {
            // linear: 13 k-pairs x 4 cols via fdot2 (vec pairs staged in halves)
            const uint4* vp4 = (const uint4*)(vpk_ + 20 * c);
            {
                const uint4 V0 = vp4[0];
                acc.x = fdot2(V0.x, wreg[0].x, acc.x); acc.y = fdot2(V0.x, wreg[0].y, acc.y);
                acc.z = fdot2(V0.x, wreg[0].z, acc.z); acc.w = fdot2(V0.x, wreg[0].w, acc.w);
                acc.x = fdot2(V0.y, wreg[1].x, acc.x); acc.y = fdot2(V0.y, wreg[1].y, acc.y);
                acc.z = fdot2(V0.y, wreg[1].z, acc.z); acc.w = fdot2(V0.y, wreg[1].w, acc.w);
                acc.x = fdot2(V0.z, wreg[2].x, acc.x); acc.y = fdot2(V0.z, wreg[2].y, acc.y);
                acc.z = fdot2(V0.z, wreg[2].z, acc.z); acc.w = fdot2(V0.z, wreg[2].w, acc.w);
                acc.x = fdot2(V0.w, wreg[3].x, acc.x); acc.y = fdot2(V0.w, wreg[3].y, acc.y);
                acc.z = fdot2(V0.w, wreg[3].z, acc.z); acc.w = fdot2(V0.w, wreg[3].w, acc.w);
            }
            {
                const uint4 V1 = vp4[1];
                acc.x = fdot2(V1.x, wreg[4].x, acc.x); acc.y = fdot2(V1.x, wreg[4].y, acc.y);
                acc.z = fdot2(V1.x, wreg[4].z, acc.z); acc.w = fdot2(V1.x, wreg[4].w, acc.w);
                acc.x = fdot2(V1.y, wreg[5].x, acc.x); acc.y = fdot2(V1.y, wreg[5].y, acc.y);
                acc.z = fdot2(V1.y, wreg[5].z, acc.z); acc.w = fdot2(V1.y, wreg[5].w, acc.w);
                acc.x = fdot2(V1.z, wreg[6].x, acc.x); acc.y = fdot2(V1.z, wreg[6].y, acc.y);
                acc.z = fdot2(V1.z, wreg[6].z, acc.z); acc.w = fdot2(V1.z, wreg[6].w, acc.w);
                acc.x = fdot2(V1.w, wreg[7].x, acc.x); acc.y = fdot2(V1.w, wreg[7].y, acc.y);
                acc.z = fdot2(V1.w, wreg[7].z, acc.z); acc.w = fdot2(V1.w, wreg[7].w, acc.w);
            }
            {
                const uint4 V2 = vp4[2];
                acc.x = fdot2(V2.x, wreg[8].x, acc.x); acc.y = fdot2(V2.x, wreg[8].y, acc.y);
                acc.z = fdot2(V2.x, wreg[8].z, acc.z); acc.w = fdot2(V2.x, wreg[8].w, acc.w);
                acc.x = fdot2(V2.y, wreg[9].x, acc.x); acc.y = fdot2(V2.y, wreg[9].y, acc.y);
                acc.z = fdot2(V2.y, wreg[9].z, acc.z); acc.w = fdot2(V2.y, wreg[9].w, acc.w);
                acc.x = fdot2(V2.z, wreg[10].x, acc.x); acc.y = fdot2(V2.z, wreg[10].y, acc.y);
                acc.z = fdot2(V2.z, wreg[10].z, acc.z); acc.w = fdot2(V2.z, wreg[10].w, acc.w);
                acc.x = fdot2(V2.w, wreg[11].x, acc.x); acc.y = fdot2(V2.w, wreg[11].y, acc.y);
                acc.z = fdot2(V2.w, wreg[11].z, acc.z); acc.w = fdot2(V2.w, wreg[11].w, acc.w);
            }
            {
                const u32 v12 = vpk_[20 * c + 12];
                acc.x = fdot2(v12, wreg[12].x, acc.x); acc.y = fdot2(v12, wreg[12].y, acc.y);
                acc.z = fdot2(v12, wreg[12].z, acc.z); acc.w = fdot2(v12, wreg[12].w, acc.w);
            }
        } else if (wv == 15) {
            __builtin_amdgcn_s_setprio(1);
            // tb = vec . w_att[D:] + b_att
            const float4 v1 = *(const float4*)(vec_ + 4 * lane);
            float4 v2 = z4;
            if (lane < 11) v2 = *(const float4*)(vec_ + 256 + 4 * lane);
            float p = v1.x*wb1.x + v1.y*wb1.y + v1.z*wb1.z + v1.w*wb1.w
                    + v2.x*wb2.x + v2.y*wb2.y + v2.z*wb2.z + v2.w*wb2.w;
            p = dpp_wave_sum(p);
            const float tb = lane63(p) + batt;
            // scores: tanh in (-1,1) -> exp safe, no max pass
            const int lb = 4 * lane;
            float e0 = 0.f, e1 = 0.f, e2 = 0.f, e3 = 0.f;
            {
                float x, E2, th;
                x = s0r.x + tb; E2 = __expf(2.f * x);
                th = 1.f - 2.f * __builtin_amdgcn_rcpf(E2 + 1.f);
                if (lb + 0 < clen) e0 = __expf(th);
                x = s0r.y + tb; E2 = __expf(2.f * x);
                th = 1.f - 2.f * __builtin_amdgcn_rcpf(E2 + 1.f);
                if (lb + 1 < clen) e1 = __expf(th);
                x = s0r.z + tb; E2 = __expf(2.f * x);
                th = 1.f - 2.f * __builtin_amdgcn_rcpf(E2 + 1.f);
                if (lb + 2 < clen) e2 = __expf(th);
                x = s0r.w + tb; E2 = __expf(2.f * x);
                th = 1.f - 2.f * __builtin_amdgcn_rcpf(E2 + 1.f);
                if (lb + 3 < clen) e3 = __expf(th);
            }
            float es = dpp_wave_sum(e0 + e1 + e2 + e3);
            const float rinv = __builtin_amdgcn_rcpf(lane63(es));
            // alpha pairs -> chunk-padded layout [cp][12]
            const int p0 = 2 * lane, p1 = p0 + 1;
            const int c0 = p0 / 11, sl0 = p0 - 11 * c0;
            const int c1 = p1 / 11, sl1 = p1 - 11 * c1;
            apk_[12 * c0 + sl0] = pk16(e0 * rinv, e1 * rinv);
            apk_[12 * c1 + sl1] = pk16(e2 * rinv, e3 * rinv);
            __builtin_amdgcn_s_setprio(0);
        }
        __syncthreads();   // apk ready

        if (heavy) {
            // attention gather: 11 l-pairs x 4 cols from E registers
            const uint4* ap4 = (const uint4*)(apk_ + 12 * c);
            {
                const uint4 A0 = ap4[0];
                if (lp0 + 0 < lps) {
                    acc.x = fdot2(A0.x, ereg[0].x, acc.x); acc.y = fdot2(A0.x, ereg[0].y, acc.y);
                    acc.z = fdot2(A0.x, ereg[0].z, acc.z); acc.w = fdot2(A0.x, ereg[0].w, acc.w);
                }
                if (lp0 + 1 < lps) {
                    acc.x = fdot2(A0.y, ereg[1].x, acc.x); acc.y = fdot2(A0.y, ereg[1].y, acc.y);
                    acc.z = fdot2(A0.y, ereg[1].z, acc.z); acc.w = fdot2(A0.y, ereg[1].w, acc.w);
                }
                if (lp0 + 2 < lps) {
                    acc.x = fdot2(A0.z, ereg[2].x, acc.x); acc.y = fdot2(A0.z, ereg[2].y, acc.y);
                    acc.z = fdot2(A0.z, ereg[2].z, acc.z); acc.w = fdot2(A0.z, ereg[2].w, acc.w);
                }
                if (lp0 + 3 < lps) {
                    acc.x = fdot2(A0.w, ereg[3].x, acc.x); acc.y = fdot2(A0.w, ereg[3].y, acc.y);
                    acc.z = fdot2(A0.w, ereg[3].z, acc.z); acc.w = fdot2(A0.w, ereg[3].w, acc.w);
                }
            }
            {
                const uint4 A1 = ap4[1];
                if (lp0 + 4 < lps) {
                    acc.x = fdot2(A1.x, ereg[4].x, acc.x); acc.y = fdot2(A1.x, ereg[4].y, acc.y);
                    acc.z = fdot2(A1.x, ereg[4].z, acc.z); acc.w = fdot2(A1.x, ereg[4].w, acc.w);
                }
                if (lp0 + 5 < lps) {
                    acc.x = fdot2(A1.y, ereg[5].x, acc.x); acc.y = fdot2(A1.y, ereg[5].y, acc.y);
                    acc.z = fdot2(A1.y, ereg[5].z, acc.z); acc.w = fdot2(A1.y, ereg[5].w, acc.w);
                }
                if (lp0 + 6 < lps) {
                    acc.x = fdot2(A1.z, ereg[6].x, acc.x); acc.y = fdot2(A1.z, ereg[6].y, acc.y);
                    acc.z = fdot2(A1.z, ereg[6].z, acc.z); acc.w = fdot2(A1.z, ereg[6].w, acc.w);
                }
                if (lp0 + 7 < lps) {
                    acc.x = fdot2(A1.w, ereg[7].x, acc.x); acc.y = fdot2(A1.w, ereg[7].y, acc.y);
                    acc.z = fdot2(A1.w, ereg[7].z, acc.z); acc.w = fdot2(A1.w, ereg[7].w, acc.w);
                }
            }
            {
                const uint4 A2 = ap4[2];
                if (lp0 + 8 < lps) {
                    acc.x = fdot2(A2.x, ereg[8].x, acc.x); acc.y = fdot2(A2.x, ereg[8].y, acc.y);
                    acc.z = fdot2(A2.x, ereg[8].z, acc.z); acc.w = fdot2(A2.x, ereg[8].w, acc.w);
                }
                if (lp0 + 9 < lps) {
                    acc.x = fdot2(A2.y, ereg[9].x, acc.x); acc.y = fdot2(A2.y, ereg[9].y, acc.y);
                    acc.z = fdot2(A2.y, ereg[9].z, acc.z); acc.w = fdot2(A2.y, ereg[9].w, acc.w);
                }
                if (lp0 + 10 < lps) {
                    acc.x = fdot2(A2.z, ereg[10].x, acc.x); acc.y = fdot2(A2.z, ereg[10].y, acc.y);
                    acc.z = fdot2(A2.z, ereg[10].z, acc.z); acc.w = fdot2(A2.z, ereg[10].w, acc.w);
                }
            }
            // combine over 12 chunks (lane stride 5): 3-level shfl tree
            float4 s;
            s.x = __shfl(acc.x, lane + 30); s.y = __shfl(acc.y, lane + 30);
            s.z = __shfl(acc.z, lane + 30); s.w = __shfl(acc.w, lane + 30);
            if (c < 6) { acc.x += s.x; acc.y += s.y; acc.z += s.z; acc.w += s.w; }
            s.x = __shfl(acc.x, lane + 15); s.y = __shfl(acc.y, lane + 15);
            s.z = __shfl(acc.z, lane + 15); s.w = __shfl(acc.w, lane + 15);
            if (c < 3) { acc.x += s.x; acc.y += s.y; acc.z += s.z; acc.w += s.w; }
            float4 u1, u2;
            u1.x = __shfl(acc.x, lane + 5);  u1.y = __shfl(acc.y, lane + 5);
            u1.z = __shfl(acc.z, lane + 5);  u1.w = __shfl(acc.w, lane + 5);
            u2.x = __shfl(acc.x, lane + 10); u2.y = __shfl(acc.y, lane + 10);
            u2.z = __shfl(acc.z, lane + 10); u2.w = __shfl(acc.w, lane + 10);
            if (c == 0) {
                float4 nv;
                nv.x = acc.x + u1.x + u2.x + blin4.x;
                nv.y = acc.y + u1.y + u2.y + blin4.y;
                nv.z = acc.z + u1.z + u2.z + blin4.z;
                nv.w = acc.w + u1.w + u2.w + blin4.w;
                *(float4*)(vec_ + 4 * q) = nv;
                const int p0 = 2 * q, p1 = p0 + 1;
                const int ca = p0 / 13, sa = p0 - 13 * ca;
                const int cb = p1 / 13, sb = p1 - 13 * cb;
                vpk_[20 * ca + sa] = pk16(nv.x, nv.y);
                vpk_[20 * cb + sb] = pk16(nv.z, nv.w);
            }
        }
        __syncthreads();   // vec + vpk ready
    }

    // ---------------- logits ----------------
    if (wv < NCLS) {
        float p = 0.f;
        for (int i = lane; i < D; i += 64)
            p += vec_[i] * w_out[i * NCLS + wv];
        p = dpp_wave_sum(p);
        if (lane == 63) out[b * NCLS + wv] = p + b_out[wv];
    }
}

extern "C" void kernel_launch(void* const* d_in, const int* in_sizes, int n_in,
                              void* d_out, int out_size, void* d_ws, size_t ws_size,
                              hipStream_t stream) {
    const float* emb     = (const float*)d_in[0];
    const float* w_lin   = (const float*)d_in[1];
    const float* b_lin   = (const float*)d_in[2];
    const float* w_att   = (const float*)d_in[3];
    const float* b_att   = (const float*)d_in[4];
    const float* w_out   = (const float*)d_in[5];
    const float* b_out   = (const float*)d_in[6];
    const int*   ctx_ids = (const int*)d_in[7];
    const int*   ctx_len = (const int*)d_in[8];
    const int*   tgt_ids = (const int*)d_in[9];
    const int*   tgt_len = (const int*)d_in[10];
    const int*   tgt_loc = (const int*)d_in[11];
    float* out = (float*)d_out;

    (void)hipFuncSetAttribute((const void*)memnet_main,
                              hipFuncAttributeMaxDynamicSharedMemorySize,
                              SMEM_BYTES);
    memnet_main<<<B, NT, SMEM_BYTES, stream>>>(
        emb, w_lin, b_lin, w_att, b_att, w_out, b_out,
        ctx_ids, ctx_len, tgt_ids, tgt_len, tgt_loc, out);
}

// Round 9
// 33.137 us; speedup vs baseline: 1.2917x; 1.2917x over previous
//
#include <hip/hip_runtime.h>

typedef unsigned short u16;
typedef unsigned int   u32;
typedef __fp16 h2t __attribute__((ext_vector_type(2)));

#define D      300
#define L      256
#define LT     8
#define B      256
#define NHOPS  6
#define NCLS   3
#define NT     1024

// LDS layout (bytes)
#define OFF_E    0          // u32 [132 lp][300 col] f16x2 pairs  158400 (rows 128..131 zero pad)
#define OFF_VEC  158400     // f32 [312]                            1248
#define OFF_VPK  159648     // u32 [12 chunks][20] vec f16 pairs     960
#define OFF_APK  160608     // u32 [12 chunks][12] alpha f16 pairs   576
#define OFF_S0   161184     // f32 [256]                            1024
#define OFF_CTX  162208     // i32 [256]                            1024
#define SMEM_BYTES 163232   // <= 163840

#define DPP_ADD(x, ctrl) \
    x += __int_as_float(__builtin_amdgcn_update_dpp(0, __float_as_int(x), ctrl, 0xf, 0xf, true))

__device__ __forceinline__ float dpp_wave_sum(float x) {
    DPP_ADD(x, 0x111);   // row_shr:1
    DPP_ADD(x, 0x112);   // row_shr:2
    DPP_ADD(x, 0x114);   // row_shr:4
    DPP_ADD(x, 0x118);   // row_shr:8
    DPP_ADD(x, 0x142);   // row_bcast:15
    DPP_ADD(x, 0x143);   // row_bcast:31
    return x;            // lane 63 holds the full 64-lane sum
}
__device__ __forceinline__ float lane63(float x) {
    return __int_as_float(__builtin_amdgcn_readlane(__float_as_int(x), 63));
}
__device__ __forceinline__ u32 pk16(float a, float b) {
    h2t r = __builtin_amdgcn_cvt_pkrtz(a, b);
    return __builtin_bit_cast(u32, r);
}
__device__ __forceinline__ float fdot2(u32 a, u32 b, float c) {
    return __builtin_amdgcn_fdot2(__builtin_bit_cast(h2t, a),
                                  __builtin_bit_cast(h2t, b), c, false);
}

__launch_bounds__(NT, 1)
__global__ void memnet_main(
    const float* __restrict__ emb,
    const float* __restrict__ w_lin,
    const float* __restrict__ b_lin,
    const float* __restrict__ w_att,
    const float* __restrict__ b_att,
    const float* __restrict__ w_out,
    const float* __restrict__ b_out,
    const int* __restrict__ ctx_ids,
    const int* __restrict__ ctx_len,
    const int* __restrict__ tgt_ids,
    const int* __restrict__ tgt_len,
    const int* __restrict__ tgt_loc,
    float* __restrict__ out)
{
    extern __shared__ char sm[];
    float* vec_ = (float*)(sm + OFF_VEC);
    u32*   vpk_ = (u32*)(sm + OFF_VPK);
    u32*   apk_ = (u32*)(sm + OFF_APK);
    float* s0_  = (float*)(sm + OFF_S0);
    int*   ctx_ = (int*)(sm + OFF_CTX);

    const int b = blockIdx.x, t = threadIdx.x;
    const int lane = t & 63, wv = t >> 6;
    const int c  = lane / 5;            // chunk 0..11 (lane<60)
    const int qi = lane - 5 * c;
    const int q  = 5 * wv + qi;         // column quad (heavy)
    const bool heavy = (wv < 15) && (lane < 60);

    const int clen = ctx_len[b], tlen = tgt_len[b], loc = tgt_loc[b];

    const float4 z4 = make_float4(0.f, 0.f, 0.f, 0.f);

    // ---------------- init ----------------
    if (t < L) { ctx_[t] = ctx_ids[b * L + t]; s0_[t] = 0.f; }
    if (t < 240) vpk_[t] = 0;
    if (t < 144) apk_[t] = 0;
    if (t >= 300 && t < 312) vec_[t] = 0.f;
    {   // zero E pad rows 128..131 (4800 B = 1200 u32)
        u32* ez = (u32*)(sm + OFF_E + 128 * 1200);
        ez[t] = 0;
        if (t < 176) ez[1024 + t] = 0;
    }
    __syncthreads();

    // ---------------- v_aspect loads issued early (consumed after staging) ---
    float arow[LT];
    if (t < D) {
        int ids[LT];
        #pragma unroll
        for (int j = 0; j < LT; ++j) ids[j] = tgt_ids[b * LT + j];
        #pragma unroll
        for (int j = 0; j < LT; ++j) {
            const int safe = (j < tlen) ? ids[j] : ids[0];
            arow[j] = emb[(long)safe * D + t];
        }
    }

    // ---------------- staging: branchless static 8-trip, pipelined ----------
    {
        float4 wa1 = ((const float4*)w_att)[lane];
        float4 wa2 = z4;
        if (lane < 11) wa2 = ((const float4*)w_att)[64 + lane];
        const float rclen = 1.f / (float)clen;
        #pragma unroll 2
        for (int it = 0; it < 8; ++it) {
            const int lp = wv + 16 * it;           // < 128
            const int l0 = 2 * lp, l1 = l0 + 1;
            const int cl0 = (l0 < clen) ? l0 : clen - 1;
            const int cl1 = (l1 < clen) ? l1 : clen - 1;
            const float4* e0 = (const float4*)(emb + (long)ctx_[cl0] * D);
            const float4* e1 = (const float4*)(emb + (long)ctx_[cl1] * D);
            const float4 a0 = e0[lane];
            const float4 a1 = e1[lane];
            float4 b0 = z4, b1 = z4;
            if (lane < 11) { b0 = e0[64 + lane]; b1 = e1[64 + lane]; }
            float d0 = a0.x*wa1.x + a0.y*wa1.y + a0.z*wa1.z + a0.w*wa1.w
                     + b0.x*wa2.x + b0.y*wa2.y + b0.z*wa2.z + b0.w*wa2.w;
            float d1 = a1.x*wa1.x + a1.y*wa1.y + a1.z*wa1.z + a1.w*wa1.w
                     + b1.x*wa2.x + b1.y*wa2.y + b1.z*wa2.z + b1.w*wa2.w;
            d0 = dpp_wave_sum(d0);
            d1 = dpp_wave_sum(d1);
            const float vl0 = (l0 < clen) ? 1.f - fabsf((float)(l0 - loc)) * rclen : 0.f;
            const float vl1 = (l1 < clen) ? 1.f - fabsf((float)(l1 - loc)) * rclen : 0.f;
            if (lane == 63) { s0_[l0] = vl0 * d0; s0_[l1] = vl1 * d1; }
            uint4 P;
            P.x = pk16(a0.x * vl0, a1.x * vl1);
            P.y = pk16(a0.y * vl0, a1.y * vl1);
            P.z = pk16(a0.z * vl0, a1.z * vl1);
            P.w = pk16(a0.w * vl0, a1.w * vl1);
            *(uint4*)(sm + OFF_E + lp * 1200 + 16 * lane) = P;
            if (lane < 11) {
                uint4 Q;
                Q.x = pk16(b0.x * vl0, b1.x * vl1);
                Q.y = pk16(b0.y * vl0, b1.y * vl1);
                Q.z = pk16(b0.z * vl0, b1.z * vl1);
                Q.w = pk16(b0.w * vl0, b1.w * vl1);
                *(uint4*)(sm + OFF_E + lp * 1200 + 1024 + 16 * lane) = Q;
            }
        }
    }

    // ---------------- v_aspect -> vec (consume early loads) ----------------
    if (t < D) {
        float s = 0.f;
        #pragma unroll
        for (int j = 0; j < LT; ++j)
            s += (j < tlen) ? arow[j] : 0.f;
        const float v = s / (float)tlen;
        vec_[t] = v;
        const float v2 = __shfl_xor(v, 1);
        if ((t & 1) == 0) {
            const int kp = t >> 1;
            const int cp = kp / 13, sl = kp - 13 * cp;
            vpk_[20 * cp + sl] = pk16(v, v2);
        }
    }

    // ---------------- W pack into registers (f16 pairs, reused 6 hops) ----
    uint4 wreg[13];
    if (heavy) {
        #pragma unroll
        for (int i = 0; i < 13; ++i) {
            const int k0 = 26 * c + 2 * i;
            float4 w0 = z4, w1 = z4;
            if (k0 < D)     w0 = *(const float4*)(w_lin + (long)k0 * D + 4 * q);
            if (k0 + 1 < D) w1 = *(const float4*)(w_lin + (long)(k0 + 1) * D + 4 * q);
            wreg[i].x = pk16(w0.x, w1.x);
            wreg[i].y = pk16(w0.y, w1.y);
            wreg[i].z = pk16(w0.z, w1.z);
            wreg[i].w = pk16(w0.w, w1.w);
        }
    }

    float4 blin4 = z4;
    if (heavy) blin4 = *(const float4*)(b_lin + 4 * q);

    // hoisted vpk write slots (c==0 lanes)
    int vwa = 0, vwb = 0;
    if (heavy && c == 0) {
        const int p0 = 2 * q, p1 = p0 + 1;
        vwa = 20 * (p0 / 13) + (p0 % 13);
        vwb = 20 * (p1 / 13) + (p1 % 13);
    }
    __syncthreads();   // E, s0, vec, vpk ready

    float4 s0r = z4, wb1 = z4, wb2 = z4;
    float batt = 0.f;
    int aw0 = 0, aw1 = 0;
    if (wv == 15) {
        s0r = *(const float4*)(s0_ + 4 * lane);
        wb1 = *(const float4*)(w_att + D + 4 * lane);
        if (lane < 11) wb2 = *(const float4*)(w_att + D + 256 + 4 * lane);
        batt = b_att[0];
        const int p0 = 2 * lane, p1 = p0 + 1;
        aw0 = 12 * (p0 / 11) + (p0 % 11);
        aw1 = 12 * (p1 / 11) + (p1 % 11);
    }

    const int lp0 = 11 * c;

    // ---------------- hops ----------------
    for (int hop = 0; hop < NHOPS; ++hop) {
        float4 acc = z4;
        if (heavy) {
            // linear: 13 k-pairs x 4 cols via fdot2
            const uint4* vp4 = (const uint4*)(vpk_ + 20 * c);
            const uint4 V0 = vp4[0], V1 = vp4[1], V2 = vp4[2];
            const u32 v12 = vpk_[20 * c + 12];
            const u32 vs[13] = {V0.x, V0.y, V0.z, V0.w,
                                V1.x, V1.y, V1.z, V1.w,
                                V2.x, V2.y, V2.z, V2.w, v12};
            #pragma unroll
            for (int i = 0; i < 13; ++i) {
                acc.x = fdot2(vs[i], wreg[i].x, acc.x);
                acc.y = fdot2(vs[i], wreg[i].y, acc.y);
                acc.z = fdot2(vs[i], wreg[i].z, acc.z);
                acc.w = fdot2(vs[i], wreg[i].w, acc.w);
            }
        } else if (wv == 15) {
            __builtin_amdgcn_s_setprio(1);
            // tb = vec . w_att[D:] + b_att
            const float4 v1 = *(const float4*)(vec_ + 4 * lane);
            float4 v2 = z4;
            if (lane < 11) v2 = *(const float4*)(vec_ + 256 + 4 * lane);
            float p = v1.x*wb1.x + v1.y*wb1.y + v1.z*wb1.z + v1.w*wb1.w
                    + v2.x*wb2.x + v2.y*wb2.y + v2.z*wb2.z + v2.w*wb2.w;
            p = dpp_wave_sum(p);
            const float tb = lane63(p) + batt;
            // scores: tanh in (-1,1) -> exp safe, no max pass
            const int lb = 4 * lane;
            float e0 = 0.f, e1 = 0.f, e2 = 0.f, e3 = 0.f;
            {
                float x, E2, th;
                x = s0r.x + tb; E2 = __expf(2.f * x);
                th = 1.f - 2.f * __builtin_amdgcn_rcpf(E2 + 1.f);
                if (lb + 0 < clen) e0 = __expf(th);
                x = s0r.y + tb; E2 = __expf(2.f * x);
                th = 1.f - 2.f * __builtin_amdgcn_rcpf(E2 + 1.f);
                if (lb + 1 < clen) e1 = __expf(th);
                x = s0r.z + tb; E2 = __expf(2.f * x);
                th = 1.f - 2.f * __builtin_amdgcn_rcpf(E2 + 1.f);
                if (lb + 2 < clen) e2 = __expf(th);
                x = s0r.w + tb; E2 = __expf(2.f * x);
                th = 1.f - 2.f * __builtin_amdgcn_rcpf(E2 + 1.f);
                if (lb + 3 < clen) e3 = __expf(th);
            }
            float es = dpp_wave_sum(e0 + e1 + e2 + e3);
            const float rinv = __builtin_amdgcn_rcpf(lane63(es));
            apk_[aw0] = pk16(e0 * rinv, e1 * rinv);
            apk_[aw1] = pk16(e2 * rinv, e3 * rinv);
            __builtin_amdgcn_s_setprio(0);
        }
        __syncthreads();   // apk ready

        if (heavy) {
            // attention gather: 11 l-pairs x 4 cols from LDS E, branchless
            const uint4* ap4 = (const uint4*)(apk_ + 12 * c);
            const uint4 A0 = ap4[0], A1 = ap4[1], A2 = ap4[2];
            const u32 as[11] = {A0.x, A0.y, A0.z, A0.w,
                                A1.x, A1.y, A1.z, A1.w,
                                A2.x, A2.y, A2.z};
            const char* ep = sm + OFF_E + lp0 * 1200 + 16 * q;
            #pragma unroll
            for (int r = 0; r < 11; ++r) {
                const uint4 e4 = *(const uint4*)(ep + r * 1200);
                acc.x = fdot2(as[r], e4.x, acc.x);
                acc.y = fdot2(as[r], e4.y, acc.y);
                acc.z = fdot2(as[r], e4.z, acc.z);
                acc.w = fdot2(as[r], e4.w, acc.w);
            }
            // combine over 12 chunks (lane stride 5): 3-level shfl tree
            float4 s;
            s.x = __shfl(acc.x, lane + 30); s.y = __shfl(acc.y, lane + 30);
            s.z = __shfl(acc.z, lane + 30); s.w = __shfl(acc.w, lane + 30);
            if (c < 6) { acc.x += s.x; acc.y += s.y; acc.z += s.z; acc.w += s.w; }
            s.x = __shfl(acc.x, lane + 15); s.y = __shfl(acc.y, lane + 15);
            s.z = __shfl(acc.z, lane + 15); s.w = __shfl(acc.w, lane + 15);
            if (c < 3) { acc.x += s.x; acc.y += s.y; acc.z += s.z; acc.w += s.w; }
            float4 u1, u2;
            u1.x = __shfl(acc.x, lane + 5);  u1.y = __shfl(acc.y, lane + 5);
            u1.z = __shfl(acc.z, lane + 5);  u1.w = __shfl(acc.w, lane + 5);
            u2.x = __shfl(acc.x, lane + 10); u2.y = __shfl(acc.y, lane + 10);
            u2.z = __shfl(acc.z, lane + 10); u2.w = __shfl(acc.w, lane + 10);
            if (c == 0) {
                float4 nv;
                nv.x = acc.x + u1.x + u2.x + blin4.x;
                nv.y = acc.y + u1.y + u2.y + blin4.y;
                nv.z = acc.z + u1.z + u2.z + blin4.z;
                nv.w = acc.w + u1.w + u2.w + blin4.w;
                *(float4*)(vec_ + 4 * q) = nv;
                vpk_[vwa] = pk16(nv.x, nv.y);
                vpk_[vwb] = pk16(nv.z, nv.w);
            }
        }
        __syncthreads();   // vec + vpk ready
    }

    // ---------------- logits ----------------
    if (wv < NCLS) {
        float p = 0.f;
        for (int i = lane; i < D; i += 64)
            p += vec_[i] * w_out[i * NCLS + wv];
        p = dpp_wave_sum(p);
        if (lane == 63) out[b * NCLS + wv] = p + b_out[wv];
    }
}

extern "C" void kernel_launch(void* const* d_in, const int* in_sizes, int n_in,
                              void* d_out, int out_size, void* d_ws, size_t ws_size,
                              hipStream_t stream) {
    const float* emb     = (const float*)d_in[0];
    const float* w_lin   = (const float*)d_in[1];
    const float* b_lin   = (const float*)d_in[2];
    const float* w_att   = (const float*)d_in[3];
    const float* b_att   = (const float*)d_in[4];
    const float* w_out   = (const float*)d_in[5];
    const float* b_out   = (const float*)d_in[6];
    const int*   ctx_ids = (const int*)d_in[7];
    const int*   ctx_len = (const int*)d_in[8];
    const int*   tgt_ids = (const int*)d_in[9];
    const int*   tgt_len = (const int*)d_in[10];
    const int*   tgt_loc = (const int*)d_in[11];
    float* out = (float*)d_out;

    (void)hipFuncSetAttribute((const void*)memnet_main,
                              hipFuncAttributeMaxDynamicSharedMemorySize,
                              SMEM_BYTES);
    memnet_main<<<B, NT, SMEM_BYTES, stream>>>(
        emb, w_lin, b_lin, w_att, b_att, w_out, b_out,
        ctx_ids, ctx_len, tgt_ids, tgt_len, tgt_loc, out);
}

// Round 10
// 32.112 us; speedup vs baseline: 1.3329x; 1.0319x over previous
//
#include <hip/hip_runtime.h>

typedef unsigned short u16;
typedef unsigned int   u32;
typedef __fp16 h2t __attribute__((ext_vector_type(2)));

#define D      300
#define L      256
#define LT     8
#define B      256
#define NHOPS  6
#define NCLS   3
#define NT     1024
#define NEPR   6            // l-pairs cached in registers (of 11)

// LDS layout (bytes)
#define OFF_E    0          // u32 [132 lp][300 col] f16x2 pairs  158400 (rows 128..131 zero pad)
#define OFF_VEC  158400     // f32 [312]                            1248
#define OFF_VPK  159648     // u32 [12 chunks][20] vec f16 pairs     960
#define OFF_APK  160608     // u32 [12 chunks][12] alpha f16 pairs   576
#define OFF_S0   161184     // f32 [256]                            1024
#define OFF_CTX  162208     // i32 [256]                            1024
#define SMEM_BYTES 163232   // <= 163840

#define DPP_ADD(x, ctrl) \
    x += __int_as_float(__builtin_amdgcn_update_dpp(0, __float_as_int(x), ctrl, 0xf, 0xf, true))

__device__ __forceinline__ float dpp_wave_sum(float x) {
    DPP_ADD(x, 0x111);   // row_shr:1
    DPP_ADD(x, 0x112);   // row_shr:2
    DPP_ADD(x, 0x114);   // row_shr:4
    DPP_ADD(x, 0x118);   // row_shr:8
    DPP_ADD(x, 0x142);   // row_bcast:15
    DPP_ADD(x, 0x143);   // row_bcast:31
    return x;            // lane 63 holds the full 64-lane sum
}
__device__ __forceinline__ float lane63(float x) {
    return __int_as_float(__builtin_amdgcn_readlane(__float_as_int(x), 63));
}
__device__ __forceinline__ u32 pk16(float a, float b) {
    h2t r = __builtin_amdgcn_cvt_pkrtz(a, b);
    return __builtin_bit_cast(u32, r);
}
__device__ __forceinline__ float fdot2(u32 a, u32 b, float c) {
    return __builtin_amdgcn_fdot2(__builtin_bit_cast(h2t, a),
                                  __builtin_bit_cast(h2t, b), c, false);
}

__global__ void
__launch_bounds__(NT)
__attribute__((amdgpu_waves_per_eu(4, 4)))
memnet_main(
    const float* __restrict__ emb,
    const float* __restrict__ w_lin,
    const float* __restrict__ b_lin,
    const float* __restrict__ w_att,
    const float* __restrict__ b_att,
    const float* __restrict__ w_out,
    const float* __restrict__ b_out,
    const int* __restrict__ ctx_ids,
    const int* __restrict__ ctx_len,
    const int* __restrict__ tgt_ids,
    const int* __restrict__ tgt_len,
    const int* __restrict__ tgt_loc,
    float* __restrict__ out)
{
    extern __shared__ char sm[];
    float* vec_ = (float*)(sm + OFF_VEC);
    u32*   vpk_ = (u32*)(sm + OFF_VPK);
    u32*   apk_ = (u32*)(sm + OFF_APK);
    float* s0_  = (float*)(sm + OFF_S0);
    int*   ctx_ = (int*)(sm + OFF_CTX);

    const int b = blockIdx.x, t = threadIdx.x;
    const int lane = t & 63, wv = t >> 6;
    const int c  = lane / 5;            // chunk 0..11 (lane<60)
    const int qi = lane - 5 * c;
    const int q  = 5 * wv + qi;         // column quad (heavy)
    const bool heavy = (wv < 15) && (lane < 60);

    const int clen = ctx_len[b], tlen = tgt_len[b], loc = tgt_loc[b];

    const float4 z4 = make_float4(0.f, 0.f, 0.f, 0.f);

    // ---------------- init ----------------
    if (t < L) { ctx_[t] = ctx_ids[b * L + t]; s0_[t] = 0.f; }
    if (t < 240) vpk_[t] = 0;
    if (t < 144) apk_[t] = 0;
    if (t >= 300 && t < 312) vec_[t] = 0.f;
    {   // zero E pad rows 128..131 (4800 B = 1200 u32)
        u32* ez = (u32*)(sm + OFF_E + 128 * 1200);
        ez[t] = 0;
        if (t < 176) ez[1024 + t] = 0;
    }
    __syncthreads();

    // ---------------- v_aspect loads issued early (consumed after staging) ---
    float arow[LT];
    if (t < D) {
        int ids[LT];
        #pragma unroll
        for (int j = 0; j < LT; ++j) ids[j] = tgt_ids[b * LT + j];
        #pragma unroll
        for (int j = 0; j < LT; ++j) {
            const int safe = (j < tlen) ? ids[j] : ids[0];
            arow[j] = emb[(long)safe * D + t];
        }
    }

    // ---------------- staging: branchless static 8-trip, pipelined ----------
    {
        float4 wa1 = ((const float4*)w_att)[lane];
        float4 wa2 = z4;
        if (lane < 11) wa2 = ((const float4*)w_att)[64 + lane];
        const float rclen = 1.f / (float)clen;
        #pragma unroll 2
        for (int it = 0; it < 8; ++it) {
            const int lp = wv + 16 * it;           // < 128
            const int l0 = 2 * lp, l1 = l0 + 1;
            const int cl0 = (l0 < clen) ? l0 : clen - 1;
            const int cl1 = (l1 < clen) ? l1 : clen - 1;
            const float4* e0 = (const float4*)(emb + (long)ctx_[cl0] * D);
            const float4* e1 = (const float4*)(emb + (long)ctx_[cl1] * D);
            const float4 a0 = e0[lane];
            const float4 a1 = e1[lane];
            float4 b0 = z4, b1 = z4;
            if (lane < 11) { b0 = e0[64 + lane]; b1 = e1[64 + lane]; }
            float d0 = a0.x*wa1.x + a0.y*wa1.y + a0.z*wa1.z + a0.w*wa1.w
                     + b0.x*wa2.x + b0.y*wa2.y + b0.z*wa2.z + b0.w*wa2.w;
            float d1 = a1.x*wa1.x + a1.y*wa1.y + a1.z*wa1.z + a1.w*wa1.w
                     + b1.x*wa2.x + b1.y*wa2.y + b1.z*wa2.z + b1.w*wa2.w;
            d0 = dpp_wave_sum(d0);
            d1 = dpp_wave_sum(d1);
            const float vl0 = (l0 < clen) ? 1.f - fabsf((float)(l0 - loc)) * rclen : 0.f;
            const float vl1 = (l1 < clen) ? 1.f - fabsf((float)(l1 - loc)) * rclen : 0.f;
            if (lane == 63) { s0_[l0] = vl0 * d0; s0_[l1] = vl1 * d1; }
            uint4 P;
            P.x = pk16(a0.x * vl0, a1.x * vl1);
            P.y = pk16(a0.y * vl0, a1.y * vl1);
            P.z = pk16(a0.z * vl0, a1.z * vl1);
            P.w = pk16(a0.w * vl0, a1.w * vl1);
            *(uint4*)(sm + OFF_E + lp * 1200 + 16 * lane) = P;
            if (lane < 11) {
                uint4 Q;
                Q.x = pk16(b0.x * vl0, b1.x * vl1);
                Q.y = pk16(b0.y * vl0, b1.y * vl1);
                Q.z = pk16(b0.z * vl0, b1.z * vl1);
                Q.w = pk16(b0.w * vl0, b1.w * vl1);
                *(uint4*)(sm + OFF_E + lp * 1200 + 1024 + 16 * lane) = Q;
            }
        }
    }

    // ---------------- v_aspect -> vec (consume early loads) ----------------
    if (t < D) {
        float s = 0.f;
        #pragma unroll
        for (int j = 0; j < LT; ++j)
            s += (j < tlen) ? arow[j] : 0.f;
        const float v = s / (float)tlen;
        vec_[t] = v;
        const float v2 = __shfl_xor(v, 1);
        if ((t & 1) == 0) {
            const int kp = t >> 1;
            const int cp = kp / 13, sl = kp - 13 * cp;
            vpk_[20 * cp + sl] = pk16(v, v2);
        }
    }

    // ---------------- W pack into registers (f16 pairs, reused 6 hops) ----
    uint4 wreg[13];
    if (heavy) {
        #pragma unroll
        for (int i = 0; i < 13; ++i) {
            const int k0 = 26 * c + 2 * i;
            float4 w0 = z4, w1 = z4;
            if (k0 < D)     w0 = *(const float4*)(w_lin + (long)k0 * D + 4 * q);
            if (k0 + 1 < D) w1 = *(const float4*)(w_lin + (long)(k0 + 1) * D + 4 * q);
            wreg[i].x = pk16(w0.x, w1.x);
            wreg[i].y = pk16(w0.y, w1.y);
            wreg[i].z = pk16(w0.z, w1.z);
            wreg[i].w = pk16(w0.w, w1.w);
        }
    }

    float4 blin4 = z4;
    if (heavy) blin4 = *(const float4*)(b_lin + 4 * q);

    // hoisted vpk write slots (c==0 lanes)
    int vwa = 0, vwb = 0;
    if (heavy && c == 0) {
        const int p0 = 2 * q, p1 = p0 + 1;
        vwa = 20 * (p0 / 13) + (p0 % 13);
        vwb = 20 * (p1 / 13) + (p1 % 13);
    }
    __syncthreads();   // E, s0, vec, vpk ready

    const int lp0 = 11 * c;

    // ---------------- E slice partial register cache (first NEPR pairs) -----
    uint4 ereg[NEPR];
    if (heavy) {
        const char* ep = sm + OFF_E + lp0 * 1200 + 16 * q;
        #pragma unroll
        for (int r = 0; r < NEPR; ++r)
            ereg[r] = *(const uint4*)(ep + r * 1200);
    }

    float4 s0r = z4, wb1 = z4, wb2 = z4;
    float batt = 0.f;
    int aw0 = 0, aw1 = 0;
    if (wv == 15) {
        s0r = *(const float4*)(s0_ + 4 * lane);
        wb1 = *(const float4*)(w_att + D + 4 * lane);
        if (lane < 11) wb2 = *(const float4*)(w_att + D + 256 + 4 * lane);
        batt = b_att[0];
        const int p0 = 2 * lane, p1 = p0 + 1;
        aw0 = 12 * (p0 / 11) + (p0 % 11);
        aw1 = 12 * (p1 / 11) + (p1 % 11);
    }

    // ---------------- hops ----------------
    for (int hop = 0; hop < NHOPS; ++hop) {
        float4 acc = z4;
        if (heavy) {
            // linear: 13 k-pairs x 4 cols via fdot2
            const uint4* vp4 = (const uint4*)(vpk_ + 20 * c);
            const uint4 V0 = vp4[0], V1 = vp4[1], V2 = vp4[2];
            const u32 v12 = vpk_[20 * c + 12];
            const u32 vs[13] = {V0.x, V0.y, V0.z, V0.w,
                                V1.x, V1.y, V1.z, V1.w,
                                V2.x, V2.y, V2.z, V2.w, v12};
            #pragma unroll
            for (int i = 0; i < 13; ++i) {
                acc.x = fdot2(vs[i], wreg[i].x, acc.x);
                acc.y = fdot2(vs[i], wreg[i].y, acc.y);
                acc.z = fdot2(vs[i], wreg[i].z, acc.z);
                acc.w = fdot2(vs[i], wreg[i].w, acc.w);
            }
        } else if (wv == 15) {
            __builtin_amdgcn_s_setprio(1);
            // tb = vec . w_att[D:] + b_att
            const float4 v1 = *(const float4*)(vec_ + 4 * lane);
            float4 v2 = z4;
            if (lane < 11) v2 = *(const float4*)(vec_ + 256 + 4 * lane);
            float p = v1.x*wb1.x + v1.y*wb1.y + v1.z*wb1.z + v1.w*wb1.w
                    + v2.x*wb2.x + v2.y*wb2.y + v2.z*wb2.z + v2.w*wb2.w;
            p = dpp_wave_sum(p);
            const float tb = lane63(p) + batt;
            // scores: tanh in (-1,1) -> exp safe, no max pass
            const int lb = 4 * lane;
            float e0 = 0.f, e1 = 0.f, e2 = 0.f, e3 = 0.f;
            {
                float x, E2, th;
                x = s0r.x + tb; E2 = __expf(2.f * x);
                th = 1.f - 2.f * __builtin_amdgcn_rcpf(E2 + 1.f);
                if (lb + 0 < clen) e0 = __expf(th);
                x = s0r.y + tb; E2 = __expf(2.f * x);
                th = 1.f - 2.f * __builtin_amdgcn_rcpf(E2 + 1.f);
                if (lb + 1 < clen) e1 = __expf(th);
                x = s0r.z + tb; E2 = __expf(2.f * x);
                th = 1.f - 2.f * __builtin_amdgcn_rcpf(E2 + 1.f);
                if (lb + 2 < clen) e2 = __expf(th);
                x = s0r.w + tb; E2 = __expf(2.f * x);
                th = 1.f - 2.f * __builtin_amdgcn_rcpf(E2 + 1.f);
                if (lb + 3 < clen) e3 = __expf(th);
            }
            float es = dpp_wave_sum(e0 + e1 + e2 + e3);
            const float rinv = __builtin_amdgcn_rcpf(lane63(es));
            apk_[aw0] = pk16(e0 * rinv, e1 * rinv);
            apk_[aw1] = pk16(e2 * rinv, e3 * rinv);
            __builtin_amdgcn_s_setprio(0);
        }
        __syncthreads();   // apk ready

        if (heavy) {
            // attention gather: NEPR pairs from regs + rest from LDS, branchless
            const uint4* ap4 = (const uint4*)(apk_ + 12 * c);
            const uint4 A0 = ap4[0], A1 = ap4[1], A2 = ap4[2];
            const u32 as[11] = {A0.x, A0.y, A0.z, A0.w,
                                A1.x, A1.y, A1.z, A1.w,
                                A2.x, A2.y, A2.z};
            #pragma unroll
            for (int r = 0; r < NEPR; ++r) {
                acc.x = fdot2(as[r], ereg[r].x, acc.x);
                acc.y = fdot2(as[r], ereg[r].y, acc.y);
                acc.z = fdot2(as[r], ereg[r].z, acc.z);
                acc.w = fdot2(as[r], ereg[r].w, acc.w);
            }
            const char* ep = sm + OFF_E + lp0 * 1200 + 16 * q;
            #pragma unroll
            for (int r = NEPR; r < 11; ++r) {
                const uint4 e4 = *(const uint4*)(ep + r * 1200);
                acc.x = fdot2(as[r], e4.x, acc.x);
                acc.y = fdot2(as[r], e4.y, acc.y);
                acc.z = fdot2(as[r], e4.z, acc.z);
                acc.w = fdot2(as[r], e4.w, acc.w);
            }
            // combine over 12 chunks (lane stride 5): 3-level shfl tree
            float4 s;
            s.x = __shfl(acc.x, lane + 30); s.y = __shfl(acc.y, lane + 30);
            s.z = __shfl(acc.z, lane + 30); s.w = __shfl(acc.w, lane + 30);
            if (c < 6) { acc.x += s.x; acc.y += s.y; acc.z += s.z; acc.w += s.w; }
            s.x = __shfl(acc.x, lane + 15); s.y = __shfl(acc.y, lane + 15);
            s.z = __shfl(acc.z, lane + 15); s.w = __shfl(acc.w, lane + 15);
            if (c < 3) { acc.x += s.x; acc.y += s.y; acc.z += s.z; acc.w += s.w; }
            float4 u1, u2;
            u1.x = __shfl(acc.x, lane + 5);  u1.y = __shfl(acc.y, lane + 5);
            u1.z = __shfl(acc.z, lane + 5);  u1.w = __shfl(acc.w, lane + 5);
            u2.x = __shfl(acc.x, lane + 10); u2.y = __shfl(acc.y, lane + 10);
            u2.z = __shfl(acc.z, lane + 10); u2.w = __shfl(acc.w, lane + 10);
            if (c == 0) {
                float4 nv;
                nv.x = acc.x + u1.x + u2.x + blin4.x;
                nv.y = acc.y + u1.y + u2.y + blin4.y;
                nv.z = acc.z + u1.z + u2.z + blin4.z;
                nv.w = acc.w + u1.w + u2.w + blin4.w;
                *(float4*)(vec_ + 4 * q) = nv;
                vpk_[vwa] = pk16(nv.x, nv.y);
                vpk_[vwb] = pk16(nv.z, nv.w);
            }
        }
        __syncthreads();   // vec + vpk ready
    }

    // ---------------- logits ----------------
    if (wv < NCLS) {
        float p = 0.f;
        for (int i = lane; i < D; i += 64)
            p += vec_[i] * w_out[i * NCLS + wv];
        p = dpp_wave_sum(p);
        if (lane == 63) out[b * NCLS + wv] = p + b_out[wv];
    }
}

extern "C" void kernel_launch(void* const* d_in, const int* in_sizes, int n_in,
                              void* d_out, int out_size, void* d_ws, size_t ws_size,
                              hipStream_t stream) {
    const float* emb     = (const float*)d_in[0];
    const float* w_lin   = (const float*)d_in[1];
    const float* b_lin   = (const float*)d_in[2];
    const float* w_att   = (const float*)d_in[3];
    const float* b_att   = (const float*)d_in[4];
    const float* w_out   = (const float*)d_in[5];
    const float* b_out   = (const float*)d_in[6];
    const int*   ctx_ids = (const int*)d_in[7];
    const int*   ctx_len = (const int*)d_in[8];
    const int*   tgt_ids = (const int*)d_in[9];
    const int*   tgt_len = (const int*)d_in[10];
    const int*   tgt_loc = (const int*)d_in[11];
    float* out = (float*)d_out;

    (void)hipFuncSetAttribute((const void*)memnet_main,
                              hipFuncAttributeMaxDynamicSharedMemorySize,
                              SMEM_BYTES);
    memnet_main<<<B, NT, SMEM_BYTES, stream>>>(
        emb, w_lin, b_lin, w_att, b_att, w_out, b_out,
        ctx_ids, ctx_len, tgt_ids, tgt_len, tgt_loc, out);
}